// Round 14
// baseline (178.840 us; speedup 1.0000x reference)
//
#include <hip/hip_runtime.h>

#define BSZ 8
#define TLEN 2048
#define CDIM 768
#define LCH 16
#define NCH (TLEN / LCH)

typedef __attribute__((ext_vector_type(4))) float f32x4;
typedef __attribute__((ext_vector_type(8))) _Float16 f16x8;   // 8 f16 = 4 VGPRs (MFMA operand)
typedef __attribute__((ext_vector_type(4))) _Float16 f16x4;
typedef __attribute__((ext_vector_type(4))) float float4v;
typedef __attribute__((ext_vector_type(2))) float float2v;

__device__ __forceinline__ float lo16(unsigned u) {
    unsigned short s = (unsigned short)u;
    _Float16 h; __builtin_memcpy(&h, &s, 2);
    return (float)h;
}
__device__ __forceinline__ float hi16(unsigned u) {
    unsigned short s = (unsigned short)(u >> 16);
    _Float16 h; __builtin_memcpy(&h, &s, 2);
    return (float)h;
}
__device__ __forceinline__ unsigned packf16(float x, float y) {
    _Float16 hx = (_Float16)x, hy = (_Float16)y;
    unsigned short sx, sy;
    __builtin_memcpy(&sx, &hx, 2); __builtin_memcpy(&sy, &hy, 2);
    return (unsigned)sx | ((unsigned)sy << 16);
}

// async global->LDS, 16B per lane; LDS dest = wave-uniform base + lane*16
#define GLD16(g, l)                                                          \
    __builtin_amdgcn_global_load_lds(                                        \
        (const __attribute__((address_space(1))) unsigned int*)(g),          \
        (__attribute__((address_space(3))) unsigned int*)(l), 16, 0, 0)

// ---------------------------------------------------------------------------
// f32 -> f16 cast, 4 elements/thread (x plane)
// ---------------------------------------------------------------------------
__global__ __launch_bounds__(256) void split_f16(const float* __restrict__ src,
                                                 _Float16* __restrict__ dst, int n4) {
    int i = blockIdx.x * 256 + threadIdx.x;
    if (i >= n4) return;
    float4v f = ((const float4v*)src)[i];
    f16x4 h;
    #pragma unroll
    for (int j = 0; j < 4; ++j) h[j] = (_Float16)f[j];
    ((f16x4*)dst)[i] = h;
}

// all 4 weight planes in one launch: blockIdx.y = plane (0..3)
__global__ __launch_bounds__(256) void split_w4(
    const float* __restrict__ Wk, const float* __restrict__ Wv,
    const float* __restrict__ Wr, const float* __restrict__ Wo,
    _Float16* __restrict__ Wcat, _Float16* __restrict__ Woh, int n4) {
    int i = blockIdx.x * 256 + threadIdx.x;
    if (i >= n4) return;
    const int plane = blockIdx.y;
    const float* src = (plane == 0) ? Wk : (plane == 1) ? Wv : (plane == 2) ? Wr : Wo;
    _Float16* dst = (plane < 3) ? (Wcat + (size_t)plane * CDIM * CDIM) : Woh;
    float4v f = ((const float4v*)src)[i];
    f16x4 h;
    #pragma unroll
    for (int j = 0; j < 4; ++j) h[j] = (_Float16)f[j];
    ((f16x4*)dst)[i] = h;
}

// ---------------------------------------------------------------------------
// m97-structure fp16 GEMM (NT) — unchanged from round 13 except block decode
// (mt fast within XCD: A-panel swept under a hot 196KB B-panel -> less FETCH).
// 128x128 tile, BK=64, 4 waves, LDS 64KB (2 blocks/CU), proven 0-conflict
// swizzle. W concatenated [NTL*128 x 768]; merged NTL=18: nt/6 -> kh|vh|srh
// (sigmoid on srh); Wo NTL=6: f32 store.
// ---------------------------------------------------------------------------
__global__ __launch_bounds__(256, 2) void gemm_128(
    const _Float16* __restrict__ A, const _Float16* __restrict__ W,
    _Float16* __restrict__ o0, _Float16* __restrict__ o1, _Float16* __restrict__ o2,
    float* __restrict__ of32, int mpx, int NTL) {
    constexpr int K = CDIM;          // 768
    constexpr int NT = K / 64;       // 12 K-tiles of 64 (=128B)
    __shared__ __align__(16) char smem[65536];   // buf b @ b*32768: A @+0, B @+16384

    const int tid  = threadIdx.x;
    const int lane = tid & 63;
    const int wid  = tid >> 6;
    const int bid  = blockIdx.x;
    const int xcd  = bid & 7;
    const int lj   = bid >> 3;
    const int nt   = lj / mpx;       // slow: B-panel reused across mt sweep
    const int mt   = lj - nt * mpx;  // fast
    const int m0   = (xcd * mpx + mt) * 128;
    const int n0   = nt * 128;       // row offset into concatenated W

    // ---- staging: seg j = tid + q*256: row j>>3, LDS chunk j&7,
    //      global chunk (j&7)^(row&7); q-invariant selector.
    const int gq = (tid & 7) ^ ((tid >> 3) & 7);
    const char* gA = (const char*)A;
    const char* gW = (const char*)W;
    const size_t gofsA = (size_t)(m0 + (tid >> 3)) * (K * 2) + gq * 16;
    const size_t gofsB = (size_t)(n0 + (tid >> 3)) * (K * 2) + gq * 16;
    const int lofs = tid * 16;

    auto STAGE = [&](int bufb, int t) {
        const size_t kb = (size_t)t * 128;
        #pragma unroll
        for (int q = 0; q < 4; ++q) {              // q: 32-row stripes (=49152B)
            GLD16(gA + gofsA + kb + (size_t)q * 49152, &smem[bufb] + lofs + q * 4096);
            GLD16(gW + gofsB + kb + (size_t)q * 49152, &smem[bufb + 16384] + lofs + q * 4096);
        }
    };

    const int wr = wid >> 1, wc = wid & 1;
    const int rl = lane & 15;
    const int kc0 = ((((lane >> 4)    ) ^ (rl & 7)) << 4);
    const int kc1 = ((((lane >> 4) + 4) ^ (rl & 7)) << 4);

    f32x4 acc[4][4];
    #pragma unroll
    for (int i = 0; i < 4; ++i)
        #pragma unroll
        for (int j = 0; j < 4; ++j)
            acc[i][j] = (f32x4){0.f, 0.f, 0.f, 0.f};

    auto COMPUTE = [&](int bufb) {
        const char* sa = &smem[bufb];
        const char* sbb = &smem[bufb + 16384];
        #pragma unroll
        for (int ks = 0; ks < 2; ++ks) {
            const int kc = ks ? kc1 : kc0;
            f16x8 a[4], b[4];
            #pragma unroll
            for (int fi = 0; fi < 4; ++fi)
                a[fi] = *(const f16x8*)(sa + (wr * 64 + fi * 16 + rl) * 128 + kc);
            #pragma unroll
            for (int fj = 0; fj < 4; ++fj)
                b[fj] = *(const f16x8*)(sbb + (wc * 64 + fj * 16 + rl) * 128 + kc);
            #pragma unroll
            for (int fi = 0; fi < 4; ++fi)
                #pragma unroll
                for (int fj = 0; fj < 4; ++fj)
                    acc[fi][fj] = __builtin_amdgcn_mfma_f32_16x16x32_f16(
                        a[fi], b[fj], acc[fi][fj], 0, 0, 0);
        }
    };

    STAGE(0, 0);
    __syncthreads();
    int buf = 0;
    for (int t = 0; t < NT; ++t) {
        if (t + 1 < NT) STAGE(buf ^ 32768, t + 1);
        COMPUTE(buf);
        __syncthreads();
        buf ^= 32768;
    }

    // ---- epilogue: D frag mapping col=lane&15, row=(lane>>4)*4+r
    const int erow0 = m0 + wr * 64 + ((lane >> 4) << 2);
    if (of32) {
        const int col0 = n0 + wc * 64 + rl;
        #pragma unroll
        for (int mf = 0; mf < 4; ++mf)
            #pragma unroll
            for (int nf = 0; nf < 4; ++nf)
                #pragma unroll
                for (int r = 0; r < 4; ++r)
                    of32[(size_t)(erow0 + mf * 16 + r) * CDIM + (col0 + nf * 16)] =
                        acc[mf][nf][r];
    } else {
        const int mat  = nt / 6;
        const int col0 = (nt - mat * 6) * 128 + wc * 64 + rl;
        _Float16* o = (mat == 0) ? o0 : ((mat == 1) ? o1 : o2);
        if (mat == 2) {
            #pragma unroll
            for (int mf = 0; mf < 4; ++mf)
                #pragma unroll
                for (int nf = 0; nf < 4; ++nf)
                    #pragma unroll
                    for (int r = 0; r < 4; ++r)
                        o[(size_t)(erow0 + mf * 16 + r) * CDIM + (col0 + nf * 16)] =
                            (_Float16)(1.0f / (1.0f + __expf(-acc[mf][nf][r])));
        } else {
            #pragma unroll
            for (int mf = 0; mf < 4; ++mf)
                #pragma unroll
                for (int nf = 0; nf < 4; ++nf)
                    #pragma unroll
                    for (int r = 0; r < 4; ++r)
                        o[(size_t)(erow0 + mf * 16 + r) * CDIM + (col0 + nf * 16)] =
                            (_Float16)acc[mf][nf][r];
        }
    }
}

// ---------------------------------------------------------------------------
// WKV — 2 channels/thread (f16x2 packed loads, float2 state I/O).
// Math identical to rounds 2-13.
// ---------------------------------------------------------------------------
#define WKV_STEP(a, bb, p, kt, vt, w)                \
    {                                                \
        const float pn = fmaxf((p) - (w), (kt));     \
        const float e1 = __expf((p) - (w) - pn);     \
        const float e2 = __expf((kt) - pn);          \
        (a)  = e1 * (a)  + e2 * (vt);                \
        (bb) = e1 * (bb) + e2;                       \
        (p)  = pn;                                   \
    }

// 384 threads = 768 channels (one (b,chunk) per block); grid (NCH, curb)
__global__ __launch_bounds__(384) void wkv_phase1(
    const _Float16* __restrict__ k, const _Float16* __restrict__ v,
    const float* __restrict__ decay,
    float* __restrict__ Sfa, float* __restrict__ Sfb, float* __restrict__ Sfp,
    float* __restrict__ Sba, float* __restrict__ Sbb, float* __restrict__ Sbp) {
    const int c0 = threadIdx.x * 2;
    const int j = blockIdx.x;
    const int b = blockIdx.y;
    const float2v d2 = *(const float2v*)(decay + c0);
    const float w0 = d2.x * (1.0f / (float)TLEN);
    const float w1 = d2.y * (1.0f / (float)TLEN);

    const size_t base = ((size_t)b * TLEN + (size_t)j * LCH) * CDIM + c0;
    unsigned kt2[LCH], vt2[LCH];
    #pragma unroll
    for (int i = 0; i < LCH; ++i) {
        kt2[i] = *(const unsigned*)(k + base + (size_t)i * CDIM);
        vt2[i] = *(const unsigned*)(v + base + (size_t)i * CDIM);
    }

    const size_t idx = ((size_t)b * NCH + j) * CDIM + c0;

    {
        float a0 = 0.f, b0 = 0.f, p0 = -1e38f, a1 = 0.f, b1 = 0.f, p1 = -1e38f;
        #pragma unroll
        for (int i = 0; i < LCH; ++i) {
            WKV_STEP(a0, b0, p0, lo16(kt2[i]), lo16(vt2[i]), w0);
            WKV_STEP(a1, b1, p1, hi16(kt2[i]), hi16(vt2[i]), w1);
        }
        *(float2v*)(Sfa + idx) = (float2v){a0, a1};
        *(float2v*)(Sfb + idx) = (float2v){b0, b1};
        *(float2v*)(Sfp + idx) = (float2v){p0, p1};
    }
    {
        float a0 = 0.f, b0 = 0.f, p0 = -1e38f, a1 = 0.f, b1 = 0.f, p1 = -1e38f;
        #pragma unroll
        for (int i = LCH - 1; i >= 0; --i) {
            WKV_STEP(a0, b0, p0, lo16(kt2[i]), lo16(vt2[i]), w0);
            WKV_STEP(a1, b1, p1, hi16(kt2[i]), hi16(vt2[i]), w1);
        }
        *(float2v*)(Sba + idx) = (float2v){a0, a1};
        *(float2v*)(Sbb + idx) = (float2v){b0, b1};
        *(float2v*)(Sbp + idx) = (float2v){p0, p1};
    }
}

#define WKV_COMBINE(a, bb, p, as, bs, ps, wL)        \
    {                                                \
        const float pn = fmaxf((p) - (wL), (ps));    \
        const float e1 = __expf((p) - (wL) - pn);    \
        const float e2 = __expf((ps) - pn);          \
        (a)  = e1 * (a)  + e2 * (as);                \
        (bb) = e1 * (bb) + e2 * (bs);                \
        (p)  = pn;                                   \
    }

// 64 thr = 128 ch; grid (CDIM/128, curb, 2); dir = blockIdx.z
__global__ __launch_bounds__(64) void wkv_phase2(
    const float* __restrict__ Sfa, const float* __restrict__ Sfb, const float* __restrict__ Sfp,
    const float* __restrict__ Sba, const float* __restrict__ Sbb, const float* __restrict__ Sbp,
    const float* __restrict__ decay,
    float* __restrict__ Lina, float* __restrict__ Linb, float* __restrict__ Linp,
    float* __restrict__ Rina, float* __restrict__ Rinb, float* __restrict__ Rinp) {
    const int c0 = (blockIdx.x * 64 + threadIdx.x) * 2;
    const int b = blockIdx.y;
    const int dir = blockIdx.z;
    const float2v d2 = *(const float2v*)(decay + c0);
    const float wL0 = d2.x * ((float)LCH / (float)TLEN);
    const float wL1 = d2.y * ((float)LCH / (float)TLEN);

    const float* Sa = dir ? Sba : Sfa;
    const float* Sb = dir ? Sbb : Sfb;
    const float* Sp = dir ? Sbp : Sfp;
    float* Oa = dir ? Rina : Lina;
    float* Ob = dir ? Rinb : Linb;
    float* Op = dir ? Rinp : Linp;

    const size_t base = (size_t)b * NCH * CDIM + c0;
    auto IDX = [&](int j) {
        return base + (size_t)(dir ? (NCH - 1 - j) : j) * CDIM;
    };

    float2v gaA[4], gbA[4], gpA[4], gaB[4], gbB[4], gpB[4];
    #pragma unroll
    for (int u = 0; u < 4; ++u) {
        const size_t id = IDX(u);
        gaA[u] = *(const float2v*)(Sa + id);
        gbA[u] = *(const float2v*)(Sb + id);
        gpA[u] = *(const float2v*)(Sp + id);
    }
    float a0 = 0.f, b0 = 0.f, p0 = -1e38f, a1 = 0.f, b1 = 0.f, p1 = -1e38f;

    for (int jg = 0; jg < NCH; jg += 8) {
        #pragma unroll
        for (int u = 0; u < 4; ++u) {
            const size_t id = IDX(jg + 4 + u);
            gaB[u] = *(const float2v*)(Sa + id);
            gbB[u] = *(const float2v*)(Sb + id);
            gpB[u] = *(const float2v*)(Sp + id);
        }
        #pragma unroll
        for (int u = 0; u < 4; ++u) {
            const size_t id = IDX(jg + u);
            *(float2v*)(Oa + id) = (float2v){a0, a1};
            *(float2v*)(Ob + id) = (float2v){b0, b1};
            *(float2v*)(Op + id) = (float2v){p0, p1};
            WKV_COMBINE(a0, b0, p0, gaA[u].x, gbA[u].x, gpA[u].x, wL0);
            WKV_COMBINE(a1, b1, p1, gaA[u].y, gbA[u].y, gpA[u].y, wL1);
        }
        if (jg + 8 < NCH) {
            #pragma unroll
            for (int u = 0; u < 4; ++u) {
                const size_t id = IDX(jg + 8 + u);
                gaA[u] = *(const float2v*)(Sa + id);
                gbA[u] = *(const float2v*)(Sb + id);
                gpA[u] = *(const float2v*)(Sp + id);
            }
        }
        #pragma unroll
        for (int u = 0; u < 4; ++u) {
            const size_t id = IDX(jg + 4 + u);
            *(float2v*)(Oa + id) = (float2v){a0, a1};
            *(float2v*)(Ob + id) = (float2v){b0, b1};
            *(float2v*)(Op + id) = (float2v){p0, p1};
            WKV_COMBINE(a0, b0, p0, gaB[u].x, gbB[u].x, gpB[u].x, wL0);
            WKV_COMBINE(a1, b1, p1, gaB[u].y, gbB[u].y, gpB[u].y, wL1);
        }
    }
}

// 384 threads = 768 channels; grid (NCH, curb). z written packed f16x2.
__global__ __launch_bounds__(384) void wkv_phase3(
    const _Float16* __restrict__ k, const _Float16* __restrict__ v,
    const _Float16* __restrict__ sr,
    const float* __restrict__ Lina, const float* __restrict__ Linb, const float* __restrict__ Linp,
    const float* __restrict__ Rina, const float* __restrict__ Rinb, const float* __restrict__ Rinp,
    const float* __restrict__ decay, const float* __restrict__ first,
    _Float16* __restrict__ zh) {
    const int c0 = threadIdx.x * 2;
    const int j = blockIdx.x;
    const int b = blockIdx.y;
    const float2v d2 = *(const float2v*)(decay + c0);
    const float2v f2 = *(const float2v*)(first + c0);
    const float w0 = d2.x * (1.0f / (float)TLEN);
    const float w1 = d2.y * (1.0f / (float)TLEN);
    const float u0 = f2.x * (1.0f / (float)TLEN);
    const float u1 = f2.y * (1.0f / (float)TLEN);

    const size_t base = ((size_t)b * TLEN + (size_t)j * LCH) * CDIM + c0;
    unsigned kt2[LCH], vt2[LCH];
    #pragma unroll
    for (int i = 0; i < LCH; ++i) {
        kt2[i] = *(const unsigned*)(k + base + (size_t)i * CDIM);
        vt2[i] = *(const unsigned*)(v + base + (size_t)i * CDIM);
    }

    const size_t idx = ((size_t)b * NCH + j) * CDIM + c0;

    float ar0[LCH], br0[LCH], pr0[LCH], ar1[LCH], br1[LCH], pr1[LCH];
    {
        float2v ra = *(const float2v*)(Rina + idx);
        float2v rb = *(const float2v*)(Rinb + idx);
        float2v rp = *(const float2v*)(Rinp + idx);
        float a0 = ra.x, b0 = rb.x, p0 = rp.x;
        float a1 = ra.y, b1 = rb.y, p1 = rp.y;
        #pragma unroll
        for (int i = LCH - 1; i >= 0; --i) {
            ar0[i] = a0; br0[i] = b0; pr0[i] = p0;
            ar1[i] = a1; br1[i] = b1; pr1[i] = p1;
            WKV_STEP(a0, b0, p0, lo16(kt2[i]), lo16(vt2[i]), w0);
            WKV_STEP(a1, b1, p1, hi16(kt2[i]), hi16(vt2[i]), w1);
        }
    }
    {
        float2v la = *(const float2v*)(Lina + idx);
        float2v lb = *(const float2v*)(Linb + idx);
        float2v lp = *(const float2v*)(Linp + idx);
        float a0 = la.x, b0 = lb.x, p0 = lp.x;
        float a1 = la.y, b1 = lb.y, p1 = lp.y;
        #pragma unroll
        for (int i = 0; i < LCH; ++i) {
            const size_t off = base + (size_t)i * CDIM;
            const unsigned sr2 = *(const unsigned*)(sr + off);
            const float kk0 = lo16(kt2[i]), vv0 = lo16(vt2[i]);
            const float kk1 = hi16(kt2[i]), vv1 = hi16(vt2[i]);

            const float ps0 = u0 + kk0;
            const float q0  = fmaxf(fmaxf(p0, pr0[i]), ps0);
            const float eL0 = __expf(p0 - q0);
            const float eR0 = __expf(pr0[i] - q0);
            const float eS0 = __expf(ps0 - q0);
            const float y0 = (eL0 * a0 + eR0 * ar0[i] + eS0 * vv0) /
                             (eL0 * b0 + eR0 * br0[i] + eS0);
            const float z0 = lo16(sr2) * y0;

            const float ps1 = u1 + kk1;
            const float q1  = fmaxf(fmaxf(p1, pr1[i]), ps1);
            const float eL1 = __expf(p1 - q1);
            const float eR1 = __expf(pr1[i] - q1);
            const float eS1 = __expf(ps1 - q1);
            const float y1 = (eL1 * a1 + eR1 * ar1[i] + eS1 * vv1) /
                             (eL1 * b1 + eR1 * br1[i] + eS1);
            const float z1 = hi16(sr2) * y1;

            *(unsigned*)(zh + off) = packf16(z0, z1);

            WKV_STEP(a0, b0, p0, kk0, vv0, w0);
            WKV_STEP(a1, b1, p1, kk1, vv1, w1);
        }
    }
}

// ---------------------------------------------------------------------------
// Driver. ws: [Wcat 3*WN f16 | Woh WN f16 | 12 state f32 planes | kh vh srh
// xh f16 planes (zh aliases xh)]. Batch-chunked to fit ws_size.
// ---------------------------------------------------------------------------
extern "C" void kernel_launch(void* const* d_in, const int* in_sizes, int n_in,
                              void* d_out, int out_size, void* d_ws, size_t ws_size,
                              hipStream_t stream) {
    const float* x     = (const float*)d_in[0];
    const float* Wk    = (const float*)d_in[1];
    const float* Wv    = (const float*)d_in[2];
    const float* Wr    = (const float*)d_in[3];
    const float* Wo    = (const float*)d_in[4];
    const float* decay = (const float*)d_in[5];
    const float* first = (const float*)d_in[6];
    float* out = (float*)d_out;

    const size_t WN = (size_t)CDIM * CDIM;
    const size_t wbytes = 4 * WN * sizeof(_Float16);
    const size_t per_b  = (size_t)TLEN * CDIM * 8 + 12ull * NCH * CDIM * 4; // 17.3 MB
    if (ws_size < wbytes + per_b) return;
    int nb = (int)((ws_size - wbytes) / per_b);
    if (nb > BSZ) nb = BSZ;

    _Float16* wsp  = (_Float16*)d_ws;
    _Float16* Wcat = wsp;                 // rows 0-767 Wk, 768-1535 Wv, 1536-2303 Wr
    _Float16* Woh  = wsp + 3 * WN;

    const size_t NE = (size_t)nb * TLEN * CDIM;
    const size_t NP = (size_t)nb * NCH * CDIM;
    float* Sfa = (float*)(wsp + 4 * WN);
    float* Sfb = Sfa + NP;  float* Sfp = Sfb + NP;
    float* Sba = Sfp + NP;  float* Sbb = Sba + NP;  float* Sbp = Sbb + NP;
    float* Lina = Sbp + NP; float* Linb = Lina + NP; float* Linp = Linb + NP;
    float* Rina = Linp + NP; float* Rinb = Rina + NP; float* Rinp = Rinb + NP;
    _Float16* kh  = (_Float16*)(Rinp + NP);
    _Float16* vh  = kh + NE;
    _Float16* srh = vh + NE;
    _Float16* xh  = srh + NE;
    _Float16* zh  = xh;   // alias: phase3 runs after the merged input GEMM

    split_w4<<<dim3((int)(WN / 1024), 4), dim3(256), 0, stream>>>(
        Wk, Wv, Wr, Wo, Wcat, Woh, (int)(WN / 4));

    for (int b0 = 0; b0 < BSZ; b0 += nb) {
        const int curb = (BSZ - b0 < nb) ? (BSZ - b0) : nb;
        const int rows = curb * TLEN;
        const float* xc = x   + (size_t)b0 * TLEN * CDIM;
        float*       oc = out + (size_t)b0 * TLEN * CDIM;

        const int n4 = rows * CDIM / 4;
        split_f16<<<dim3(n4 / 256), dim3(256), 0, stream>>>(xc, xh, n4);

        const int mtiles = rows / 128;     // divisible by 8
        const int mpx    = mtiles / 8;

        // merged k|v|sr GEMM: Wcat 2304 rows -> 18 ntiles of 128
        gemm_128<<<dim3(mtiles * 18), dim3(256), 0, stream>>>(
            xh, Wcat, kh, vh, srh, nullptr, mpx, 18);

        wkv_phase1<<<dim3(NCH, curb), dim3(384), 0, stream>>>(
            kh, vh, decay, Sfa, Sfb, Sfp, Sba, Sbb, Sbp);
        wkv_phase2<<<dim3(CDIM / 128, curb, 2), dim3(64), 0, stream>>>(
            Sfa, Sfb, Sfp, Sba, Sbb, Sbp, decay,
            Lina, Linb, Linp, Rina, Rinb, Rinp);
        wkv_phase3<<<dim3(NCH, curb), dim3(384), 0, stream>>>(
            kh, vh, srh, Lina, Linb, Linp, Rina, Rinb, Rinp, decay, first, zh);

        // Wo GEMM: 6 ntiles of 128, f32 output
        gemm_128<<<dim3(mtiles * 6), dim3(256), 0, stream>>>(
            zh, Woh, nullptr, nullptr, nullptr, oc, mpx, 6);
    }
}

// Round 15
// 163.150 us; speedup vs baseline: 1.0962x; 1.0962x over previous
//
#include <hip/hip_runtime.h>

#define BSZ 8
#define TLEN 2048
#define CDIM 768
#define LCH 16
#define NCH (TLEN / LCH)

typedef __attribute__((ext_vector_type(4))) float f32x4;
typedef __attribute__((ext_vector_type(8))) _Float16 f16x8;   // 8 f16 = 4 VGPRs (MFMA operand)
typedef __attribute__((ext_vector_type(4))) _Float16 f16x4;
typedef __attribute__((ext_vector_type(4))) float float4v;
typedef __attribute__((ext_vector_type(2))) float float2v;

__device__ __forceinline__ float lo16(unsigned u) {
    unsigned short s = (unsigned short)u;
    _Float16 h; __builtin_memcpy(&h, &s, 2);
    return (float)h;
}
__device__ __forceinline__ float hi16(unsigned u) {
    unsigned short s = (unsigned short)(u >> 16);
    _Float16 h; __builtin_memcpy(&h, &s, 2);
    return (float)h;
}

// async global->LDS, 16B per lane; LDS dest = wave-uniform base + lane*16
#define GLD16(g, l)                                                          \
    __builtin_amdgcn_global_load_lds(                                        \
        (const __attribute__((address_space(1))) unsigned int*)(g),          \
        (__attribute__((address_space(3))) unsigned int*)(l), 16, 0, 0)

// ---------------------------------------------------------------------------
// f32 -> f16 cast, 4 elements/thread (x plane)
// ---------------------------------------------------------------------------
__global__ __launch_bounds__(256) void split_f16(const float* __restrict__ src,
                                                 _Float16* __restrict__ dst, int n4) {
    int i = blockIdx.x * 256 + threadIdx.x;
    if (i >= n4) return;
    float4v f = ((const float4v*)src)[i];
    f16x4 h;
    #pragma unroll
    for (int j = 0; j < 4; ++j) h[j] = (_Float16)f[j];
    ((f16x4*)dst)[i] = h;
}

// all 4 weight planes in one launch: blockIdx.y = plane (0..3)
__global__ __launch_bounds__(256) void split_w4(
    const float* __restrict__ Wk, const float* __restrict__ Wv,
    const float* __restrict__ Wr, const float* __restrict__ Wo,
    _Float16* __restrict__ Wcat, _Float16* __restrict__ Woh, int n4) {
    int i = blockIdx.x * 256 + threadIdx.x;
    if (i >= n4) return;
    const int plane = blockIdx.y;
    const float* src = (plane == 0) ? Wk : (plane == 1) ? Wv : (plane == 2) ? Wr : Wo;
    _Float16* dst = (plane < 3) ? (Wcat + (size_t)plane * CDIM * CDIM) : Woh;
    float4v f = ((const float4v*)src)[i];
    f16x4 h;
    #pragma unroll
    for (int j = 0; j < 4; ++j) h[j] = (_Float16)f[j];
    ((f16x4*)dst)[i] = h;
}

// ---------------------------------------------------------------------------
// m97-structure fp16 GEMM (NT): 128x128 tile, BK=64, 4 waves, LDS 64KB
// (2 blocks/CU), proven 0-conflict swizzle. nt slow within XCD (B-panel hot).
// W concatenated [NTL*128 x 768]; merged NTL=18: nt/6 -> kh|vh|srh (sigmoid
// on srh); Wo NTL=6: f32 store to of32.
// ---------------------------------------------------------------------------
__global__ __launch_bounds__(256, 2) void gemm_128(
    const _Float16* __restrict__ A, const _Float16* __restrict__ W,
    _Float16* __restrict__ o0, _Float16* __restrict__ o1, _Float16* __restrict__ o2,
    float* __restrict__ of32, int mpx, int NTL) {
    constexpr int K = CDIM;          // 768
    constexpr int NT = K / 64;       // 12 K-tiles of 64 (=128B)
    __shared__ __align__(16) char smem[65536];   // buf b @ b*32768: A @+0, B @+16384

    const int tid  = threadIdx.x;
    const int lane = tid & 63;
    const int wid  = tid >> 6;
    const int bid  = blockIdx.x;
    const int xcd  = bid & 7;
    const int lj   = bid >> 3;
    const int nt   = lj / mpx;       // slow: B-panel reused across mt sweep
    const int mt   = lj - nt * mpx;  // fast
    const int m0   = (xcd * mpx + mt) * 128;
    const int n0   = nt * 128;       // row offset into concatenated W

    const int gq = (tid & 7) ^ ((tid >> 3) & 7);
    const char* gA = (const char*)A;
    const char* gW = (const char*)W;
    const size_t gofsA = (size_t)(m0 + (tid >> 3)) * (K * 2) + gq * 16;
    const size_t gofsB = (size_t)(n0 + (tid >> 3)) * (K * 2) + gq * 16;
    const int lofs = tid * 16;

    auto STAGE = [&](int bufb, int t) {
        const size_t kb = (size_t)t * 128;
        #pragma unroll
        for (int q = 0; q < 4; ++q) {              // q: 32-row stripes (=49152B)
            GLD16(gA + gofsA + kb + (size_t)q * 49152, &smem[bufb] + lofs + q * 4096);
            GLD16(gW + gofsB + kb + (size_t)q * 49152, &smem[bufb + 16384] + lofs + q * 4096);
        }
    };

    const int wr = wid >> 1, wc = wid & 1;
    const int rl = lane & 15;
    const int kc0 = ((((lane >> 4)    ) ^ (rl & 7)) << 4);
    const int kc1 = ((((lane >> 4) + 4) ^ (rl & 7)) << 4);

    f32x4 acc[4][4];
    #pragma unroll
    for (int i = 0; i < 4; ++i)
        #pragma unroll
        for (int j = 0; j < 4; ++j)
            acc[i][j] = (f32x4){0.f, 0.f, 0.f, 0.f};

    auto COMPUTE = [&](int bufb) {
        const char* sa = &smem[bufb];
        const char* sbb = &smem[bufb + 16384];
        #pragma unroll
        for (int ks = 0; ks < 2; ++ks) {
            const int kc = ks ? kc1 : kc0;
            f16x8 a[4], b[4];
            #pragma unroll
            for (int fi = 0; fi < 4; ++fi)
                a[fi] = *(const f16x8*)(sa + (wr * 64 + fi * 16 + rl) * 128 + kc);
            #pragma unroll
            for (int fj = 0; fj < 4; ++fj)
                b[fj] = *(const f16x8*)(sbb + (wc * 64 + fj * 16 + rl) * 128 + kc);
            #pragma unroll
            for (int fi = 0; fi < 4; ++fi)
                #pragma unroll
                for (int fj = 0; fj < 4; ++fj)
                    acc[fi][fj] = __builtin_amdgcn_mfma_f32_16x16x32_f16(
                        a[fi], b[fj], acc[fi][fj], 0, 0, 0);
        }
    };

    STAGE(0, 0);
    __syncthreads();
    int buf = 0;
    for (int t = 0; t < NT; ++t) {
        if (t + 1 < NT) STAGE(buf ^ 32768, t + 1);
        COMPUTE(buf);
        __syncthreads();
        buf ^= 32768;
    }

    // ---- epilogue: D frag mapping col=lane&15, row=(lane>>4)*4+r
    const int erow0 = m0 + wr * 64 + ((lane >> 4) << 2);
    if (of32) {
        const int col0 = n0 + wc * 64 + rl;
        #pragma unroll
        for (int mf = 0; mf < 4; ++mf)
            #pragma unroll
            for (int nf = 0; nf < 4; ++nf)
                #pragma unroll
                for (int r = 0; r < 4; ++r)
                    of32[(size_t)(erow0 + mf * 16 + r) * CDIM + (col0 + nf * 16)] =
                        acc[mf][nf][r];
    } else {
        const int mat  = nt / 6;
        const int col0 = (nt - mat * 6) * 128 + wc * 64 + rl;
        _Float16* o = (mat == 0) ? o0 : ((mat == 1) ? o1 : o2);
        if (mat == 2) {
            #pragma unroll
            for (int mf = 0; mf < 4; ++mf)
                #pragma unroll
                for (int nf = 0; nf < 4; ++nf)
                    #pragma unroll
                    for (int r = 0; r < 4; ++r)
                        o[(size_t)(erow0 + mf * 16 + r) * CDIM + (col0 + nf * 16)] =
                            (_Float16)(1.0f / (1.0f + __expf(-acc[mf][nf][r])));
        } else {
            #pragma unroll
            for (int mf = 0; mf < 4; ++mf)
                #pragma unroll
                for (int nf = 0; nf < 4; ++nf)
                    #pragma unroll
                    for (int r = 0; r < 4; ++r)
                        o[(size_t)(erow0 + mf * 16 + r) * CDIM + (col0 + nf * 16)] =
                            (_Float16)acc[mf][nf][r];
        }
    }
}

// ---------------------------------------------------------------------------
// WKV (math verified rounds 2-14)
// ---------------------------------------------------------------------------
#define WKV_STEP(a, bb, p, kt, vt, w)                \
    {                                                \
        const float pn = fmaxf((p) - (w), (kt));     \
        const float e1 = __expf((p) - (w) - pn);     \
        const float e2 = __expf((kt) - pn);          \
        (a)  = e1 * (a)  + e2 * (vt);                \
        (bb) = e1 * (bb) + e2;                       \
        (p)  = pn;                                   \
    }

// phase1: 2 ch/thread (KEPT from r14: ~60 VGPR, halved load count, full occ).
// 384 threads = 768 channels; grid (NCH, curb).
__global__ __launch_bounds__(384) void wkv_phase1(
    const _Float16* __restrict__ k, const _Float16* __restrict__ v,
    const float* __restrict__ decay,
    float* __restrict__ Sfa, float* __restrict__ Sfb, float* __restrict__ Sfp,
    float* __restrict__ Sba, float* __restrict__ Sbb, float* __restrict__ Sbp) {
    const int c0 = threadIdx.x * 2;
    const int j = blockIdx.x;
    const int b = blockIdx.y;
    const float2v d2 = *(const float2v*)(decay + c0);
    const float w0 = d2.x * (1.0f / (float)TLEN);
    const float w1 = d2.y * (1.0f / (float)TLEN);

    const size_t base = ((size_t)b * TLEN + (size_t)j * LCH) * CDIM + c0;
    unsigned kt2[LCH], vt2[LCH];
    #pragma unroll
    for (int i = 0; i < LCH; ++i) {
        kt2[i] = *(const unsigned*)(k + base + (size_t)i * CDIM);
        vt2[i] = *(const unsigned*)(v + base + (size_t)i * CDIM);
    }

    const size_t idx = ((size_t)b * NCH + j) * CDIM + c0;

    {
        float a0 = 0.f, b0 = 0.f, p0 = -1e38f, a1 = 0.f, b1 = 0.f, p1 = -1e38f;
        #pragma unroll
        for (int i = 0; i < LCH; ++i) {
            WKV_STEP(a0, b0, p0, lo16(kt2[i]), lo16(vt2[i]), w0);
            WKV_STEP(a1, b1, p1, hi16(kt2[i]), hi16(vt2[i]), w1);
        }
        *(float2v*)(Sfa + idx) = (float2v){a0, a1};
        *(float2v*)(Sfb + idx) = (float2v){b0, b1};
        *(float2v*)(Sfp + idx) = (float2v){p0, p1};
    }
    {
        float a0 = 0.f, b0 = 0.f, p0 = -1e38f, a1 = 0.f, b1 = 0.f, p1 = -1e38f;
        #pragma unroll
        for (int i = LCH - 1; i >= 0; --i) {
            WKV_STEP(a0, b0, p0, lo16(kt2[i]), lo16(vt2[i]), w0);
            WKV_STEP(a1, b1, p1, hi16(kt2[i]), hi16(vt2[i]), w1);
        }
        *(float2v*)(Sba + idx) = (float2v){a0, a1};
        *(float2v*)(Sbb + idx) = (float2v){b0, b1};
        *(float2v*)(Sbp + idx) = (float2v){p0, p1};
    }
}

#define WKV_COMBINE(a, bb, p, as, bs, ps, wL)        \
    {                                                \
        const float pn = fmaxf((p) - (wL), (ps));    \
        const float e1 = __expf((p) - (wL) - pn);    \
        const float e2 = __expf((ps) - pn);          \
        (a)  = e1 * (a)  + e2 * (as);                \
        (bb) = e1 * (bb) + e2 * (bs);                \
        (p)  = pn;                                   \
    }

// phase2: REVERTED to 1 ch/thread (latency-bound: max threads wins).
// grid (CDIM/64, curb, 2); dir = blockIdx.z. Software-pipelined (groups of 4).
__global__ __launch_bounds__(64) void wkv_phase2(
    const float* __restrict__ Sfa, const float* __restrict__ Sfb, const float* __restrict__ Sfp,
    const float* __restrict__ Sba, const float* __restrict__ Sbb, const float* __restrict__ Sbp,
    const float* __restrict__ decay,
    float* __restrict__ Lina, float* __restrict__ Linb, float* __restrict__ Linp,
    float* __restrict__ Rina, float* __restrict__ Rinb, float* __restrict__ Rinp) {
    const int c = blockIdx.x * 64 + threadIdx.x;
    const int b = blockIdx.y;
    const int dir = blockIdx.z;
    const float wL = decay[c] * ((float)LCH / (float)TLEN);

    const float* Sa = dir ? Sba : Sfa;
    const float* Sb = dir ? Sbb : Sfb;
    const float* Sp = dir ? Sbp : Sfp;
    float* Oa = dir ? Rina : Lina;
    float* Ob = dir ? Rinb : Linb;
    float* Op = dir ? Rinp : Linp;

    const size_t base = (size_t)b * NCH * CDIM + c;
    auto IDX = [&](int j) {
        return base + (size_t)(dir ? (NCH - 1 - j) : j) * CDIM;
    };

    float gaA[4], gbA[4], gpA[4], gaB[4], gbB[4], gpB[4];
    #pragma unroll
    for (int u = 0; u < 4; ++u) {
        const size_t id = IDX(u);
        gaA[u] = Sa[id]; gbA[u] = Sb[id]; gpA[u] = Sp[id];
    }
    float a = 0.0f, bb = 0.0f, p = -1e38f;

    for (int jg = 0; jg < NCH; jg += 8) {
        #pragma unroll
        for (int u = 0; u < 4; ++u) {
            const size_t id = IDX(jg + 4 + u);
            gaB[u] = Sa[id]; gbB[u] = Sb[id]; gpB[u] = Sp[id];
        }
        #pragma unroll
        for (int u = 0; u < 4; ++u) {
            const size_t id = IDX(jg + u);
            Oa[id] = a; Ob[id] = bb; Op[id] = p;
            WKV_COMBINE(a, bb, p, gaA[u], gbA[u], gpA[u], wL);
        }
        if (jg + 8 < NCH) {
            #pragma unroll
            for (int u = 0; u < 4; ++u) {
                const size_t id = IDX(jg + 8 + u);
                gaA[u] = Sa[id]; gbA[u] = Sb[id]; gpA[u] = Sp[id];
            }
        }
        #pragma unroll
        for (int u = 0; u < 4; ++u) {
            const size_t id = IDX(jg + 4 + u);
            Oa[id] = a; Ob[id] = bb; Op[id] = p;
            WKV_COMBINE(a, bb, p, gaB[u], gbB[u], gpB[u], wL);
        }
    }
}

// phase3: REVERTED to 1 ch/thread (per-position arrays double at 2ch ->
// occupancy cliff). grid (CDIM/256, NCH, curb), 256 thr.
__global__ __launch_bounds__(256) void wkv_phase3(
    const _Float16* __restrict__ k, const _Float16* __restrict__ v,
    const _Float16* __restrict__ sr,
    const float* __restrict__ Lina, const float* __restrict__ Linb, const float* __restrict__ Linp,
    const float* __restrict__ Rina, const float* __restrict__ Rinb, const float* __restrict__ Rinp,
    const float* __restrict__ decay, const float* __restrict__ first,
    _Float16* __restrict__ zh) {
    const int c = blockIdx.x * 256 + threadIdx.x;
    const int j = blockIdx.y;
    const int b = blockIdx.z;
    const float w = decay[c] * (1.0f / (float)TLEN);
    const float u = first[c] * (1.0f / (float)TLEN);

    const size_t base = ((size_t)b * TLEN + (size_t)j * LCH) * CDIM + c;
    float kt[LCH], vt[LCH];
    #pragma unroll
    for (int i = 0; i < LCH; ++i) {
        kt[i] = (float)k[base + (size_t)i * CDIM];
        vt[i] = (float)v[base + (size_t)i * CDIM];
    }

    const size_t idx = ((size_t)b * NCH + j) * CDIM + c;

    float ar[LCH], br[LCH], pr[LCH];
    {
        float a = Rina[idx], bb = Rinb[idx], p = Rinp[idx];
        #pragma unroll
        for (int i = LCH - 1; i >= 0; --i) {
            ar[i] = a; br[i] = bb; pr[i] = p;
            WKV_STEP(a, bb, p, kt[i], vt[i], w);
        }
    }
    {
        float a = Lina[idx], bb = Linb[idx], p = Linp[idx];
        #pragma unroll
        for (int i = 0; i < LCH; ++i) {
            const size_t off = base + (size_t)i * CDIM;
            const float srt = (float)sr[off];
            const float ps = u + kt[i];
            const float q  = fmaxf(fmaxf(p, pr[i]), ps);
            const float eL = __expf(p - q);
            const float eR = __expf(pr[i] - q);
            const float eS = __expf(ps - q);
            const float num = eL * a  + eR * ar[i] + eS * vt[i];
            const float den = eL * bb + eR * br[i] + eS;
            zh[off] = (_Float16)(srt * (num / den));
            WKV_STEP(a, bb, p, kt[i], vt[i], w);
        }
    }
}

// ---------------------------------------------------------------------------
// Driver. ws: [Wcat 3*WN f16 | Woh WN f16 | 12 state f32 planes | kh vh srh
// xh f16 planes (zh aliases xh)]. Batch-chunked to fit ws_size.
// ---------------------------------------------------------------------------
extern "C" void kernel_launch(void* const* d_in, const int* in_sizes, int n_in,
                              void* d_out, int out_size, void* d_ws, size_t ws_size,
                              hipStream_t stream) {
    const float* x     = (const float*)d_in[0];
    const float* Wk    = (const float*)d_in[1];
    const float* Wv    = (const float*)d_in[2];
    const float* Wr    = (const float*)d_in[3];
    const float* Wo    = (const float*)d_in[4];
    const float* decay = (const float*)d_in[5];
    const float* first = (const float*)d_in[6];
    float* out = (float*)d_out;

    const size_t WN = (size_t)CDIM * CDIM;
    const size_t wbytes = 4 * WN * sizeof(_Float16);
    const size_t per_b  = (size_t)TLEN * CDIM * 8 + 12ull * NCH * CDIM * 4; // 17.3 MB
    if (ws_size < wbytes + per_b) return;
    int nb = (int)((ws_size - wbytes) / per_b);
    if (nb > BSZ) nb = BSZ;

    _Float16* wsp  = (_Float16*)d_ws;
    _Float16* Wcat = wsp;                 // rows 0-767 Wk, 768-1535 Wv, 1536-2303 Wr
    _Float16* Woh  = wsp + 3 * WN;

    const size_t NE = (size_t)nb * TLEN * CDIM;
    const size_t NP = (size_t)nb * NCH * CDIM;
    float* Sfa = (float*)(wsp + 4 * WN);
    float* Sfb = Sfa + NP;  float* Sfp = Sfb + NP;
    float* Sba = Sfp + NP;  float* Sbb = Sba + NP;  float* Sbp = Sbb + NP;
    float* Lina = Sbp + NP; float* Linb = Lina + NP; float* Linp = Linb + NP;
    float* Rina = Linp + NP; float* Rinb = Rina + NP; float* Rinp = Rinb + NP;
    _Float16* kh  = (_Float16*)(Rinp + NP);
    _Float16* vh  = kh + NE;
    _Float16* srh = vh + NE;
    _Float16* xh  = srh + NE;
    _Float16* zh  = xh;   // alias: phase3 runs after the merged input GEMM

    split_w4<<<dim3((int)(WN / 1024), 4), dim3(256), 0, stream>>>(
        Wk, Wv, Wr, Wo, Wcat, Woh, (int)(WN / 4));

    for (int b0 = 0; b0 < BSZ; b0 += nb) {
        const int curb = (BSZ - b0 < nb) ? (BSZ - b0) : nb;
        const int rows = curb * TLEN;
        const float* xc = x   + (size_t)b0 * TLEN * CDIM;
        float*       oc = out + (size_t)b0 * TLEN * CDIM;

        const int n4 = rows * CDIM / 4;
        split_f16<<<dim3(n4 / 256), dim3(256), 0, stream>>>(xc, xh, n4);

        const int mtiles = rows / 128;     // divisible by 8
        const int mpx    = mtiles / 8;

        // merged k|v|sr GEMM: Wcat 2304 rows -> 18 ntiles of 128
        gemm_128<<<dim3(mtiles * 18), dim3(256), 0, stream>>>(
            xh, Wcat, kh, vh, srh, nullptr, mpx, 18);

        wkv_phase1<<<dim3(NCH, curb), dim3(384), 0, stream>>>(
            kh, vh, decay, Sfa, Sfb, Sfp, Sba, Sbb, Sbp);
        wkv_phase2<<<dim3(CDIM / 64, curb, 2), dim3(64), 0, stream>>>(
            Sfa, Sfb, Sfp, Sba, Sbb, Sbp, decay,
            Lina, Linb, Linp, Rina, Rinb, Rinp);
        wkv_phase3<<<dim3(CDIM / 256, NCH, curb), dim3(256), 0, stream>>>(
            kh, vh, srh, Lina, Linb, Linp, Rina, Rinb, Rinp, decay, first, zh);

        // Wo GEMM: 6 ntiles of 128, f32 output
        gemm_128<<<dim3(mtiles * 6), dim3(256), 0, stream>>>(
            zh, Woh, nullptr, nullptr, nullptr, oc, mpx, 6);
    }
}

// Round 16
// 161.753 us; speedup vs baseline: 1.1056x; 1.0086x over previous
//
#include <hip/hip_runtime.h>

#define BSZ 8
#define TLEN 2048
#define CDIM 768
#define LCH 16
#define NCH (TLEN / LCH)

typedef __attribute__((ext_vector_type(4))) float f32x4;
typedef __attribute__((ext_vector_type(8))) _Float16 f16x8;   // 8 f16 = 4 VGPRs (MFMA operand)
typedef __attribute__((ext_vector_type(4))) _Float16 f16x4;
typedef __attribute__((ext_vector_type(4))) float float4v;
typedef __attribute__((ext_vector_type(2))) float float2v;

__device__ __forceinline__ float lo16(unsigned u) {
    unsigned short s = (unsigned short)u;
    _Float16 h; __builtin_memcpy(&h, &s, 2);
    return (float)h;
}
__device__ __forceinline__ float hi16(unsigned u) {
    unsigned short s = (unsigned short)(u >> 16);
    _Float16 h; __builtin_memcpy(&h, &s, 2);
    return (float)h;
}

// async global->LDS, 16B per lane; LDS dest = wave-uniform base + lane*16
#define GLD16(g, l)                                                          \
    __builtin_amdgcn_global_load_lds(                                        \
        (const __attribute__((address_space(1))) unsigned int*)(g),          \
        (__attribute__((address_space(3))) unsigned int*)(l), 16, 0, 0)

// ---------------------------------------------------------------------------
// f32 -> f16 cast, 4 elements/thread (x plane)
// ---------------------------------------------------------------------------
__global__ __launch_bounds__(256) void split_f16(const float* __restrict__ src,
                                                 _Float16* __restrict__ dst, int n4) {
    int i = blockIdx.x * 256 + threadIdx.x;
    if (i >= n4) return;
    float4v f = ((const float4v*)src)[i];
    f16x4 h;
    #pragma unroll
    for (int j = 0; j < 4; ++j) h[j] = (_Float16)f[j];
    ((f16x4*)dst)[i] = h;
}

// all 4 weight planes in one launch: blockIdx.y = plane (0..3)
__global__ __launch_bounds__(256) void split_w4(
    const float* __restrict__ Wk, const float* __restrict__ Wv,
    const float* __restrict__ Wr, const float* __restrict__ Wo,
    _Float16* __restrict__ Wcat, _Float16* __restrict__ Woh, int n4) {
    int i = blockIdx.x * 256 + threadIdx.x;
    if (i >= n4) return;
    const int plane = blockIdx.y;
    const float* src = (plane == 0) ? Wk : (plane == 1) ? Wv : (plane == 2) ? Wr : Wo;
    _Float16* dst = (plane < 3) ? (Wcat + (size_t)plane * CDIM * CDIM) : Woh;
    float4v f = ((const float4v*)src)[i];
    f16x4 h;
    #pragma unroll
    for (int j = 0; j < 4; ++j) h[j] = (_Float16)f[j];
    ((f16x4*)dst)[i] = h;
}

// ---------------------------------------------------------------------------
// m97-structure fp16 GEMM (NT): 128x128 tile, BK=64, 4 waves, LDS 64KB
// (2 blocks/CU), proven 0-conflict swizzle.
// Two-level decode within XCD: mt-groups of G=8 (A sub-panel 1.5MB stays
// L2-resident across the full nt sweep; B re-fetched only mpx/G times).
// W concatenated [NTL*128 x 768]; merged NTL=18: nt/6 -> kh|vh|srh (sigmoid
// on srh); Wo NTL=6: f32 store to of32.
// ---------------------------------------------------------------------------
__global__ __launch_bounds__(256, 2) void gemm_128(
    const _Float16* __restrict__ A, const _Float16* __restrict__ W,
    _Float16* __restrict__ o0, _Float16* __restrict__ o1, _Float16* __restrict__ o2,
    float* __restrict__ of32, int mpx, int NTL) {
    constexpr int K = CDIM;          // 768
    constexpr int NT = K / 64;       // 12 K-tiles of 64 (=128B)
    __shared__ __align__(16) char smem[65536];   // buf b @ b*32768: A @+0, B @+16384

    const int tid  = threadIdx.x;
    const int lane = tid & 63;
    const int wid  = tid >> 6;
    const int bid  = blockIdx.x;
    const int xcd  = bid & 7;
    const int lj   = bid >> 3;
    // two-level: group of G mtiles, nt sweeps within group
    const int G    = (mpx % 8 == 0) ? 8 : mpx;
    const int gsz  = G * NTL;
    const int grp  = lj / gsz;
    const int rem  = lj - grp * gsz;
    const int nt   = rem / G;
    const int mt   = grp * G + (rem - nt * G);
    const int m0   = (xcd * mpx + mt) * 128;
    const int n0   = nt * 128;       // row offset into concatenated W

    const int gq = (tid & 7) ^ ((tid >> 3) & 7);
    const char* gA = (const char*)A;
    const char* gW = (const char*)W;
    const size_t gofsA = (size_t)(m0 + (tid >> 3)) * (K * 2) + gq * 16;
    const size_t gofsB = (size_t)(n0 + (tid >> 3)) * (K * 2) + gq * 16;
    const int lofs = tid * 16;

    auto STAGE = [&](int bufb, int t) {
        const size_t kb = (size_t)t * 128;
        #pragma unroll
        for (int q = 0; q < 4; ++q) {              // q: 32-row stripes (=49152B)
            GLD16(gA + gofsA + kb + (size_t)q * 49152, &smem[bufb] + lofs + q * 4096);
            GLD16(gW + gofsB + kb + (size_t)q * 49152, &smem[bufb + 16384] + lofs + q * 4096);
        }
    };

    const int wr = wid >> 1, wc = wid & 1;
    const int rl = lane & 15;
    const int kc0 = ((((lane >> 4)    ) ^ (rl & 7)) << 4);
    const int kc1 = ((((lane >> 4) + 4) ^ (rl & 7)) << 4);

    f32x4 acc[4][4];
    #pragma unroll
    for (int i = 0; i < 4; ++i)
        #pragma unroll
        for (int j = 0; j < 4; ++j)
            acc[i][j] = (f32x4){0.f, 0.f, 0.f, 0.f};

    auto COMPUTE = [&](int bufb) {
        const char* sa = &smem[bufb];
        const char* sbb = &smem[bufb + 16384];
        #pragma unroll
        for (int ks = 0; ks < 2; ++ks) {
            const int kc = ks ? kc1 : kc0;
            f16x8 a[4], b[4];
            #pragma unroll
            for (int fi = 0; fi < 4; ++fi)
                a[fi] = *(const f16x8*)(sa + (wr * 64 + fi * 16 + rl) * 128 + kc);
            #pragma unroll
            for (int fj = 0; fj < 4; ++fj)
                b[fj] = *(const f16x8*)(sbb + (wc * 64 + fj * 16 + rl) * 128 + kc);
            #pragma unroll
            for (int fi = 0; fi < 4; ++fi)
                #pragma unroll
                for (int fj = 0; fj < 4; ++fj)
                    acc[fi][fj] = __builtin_amdgcn_mfma_f32_16x16x32_f16(
                        a[fi], b[fj], acc[fi][fj], 0, 0, 0);
        }
    };

    STAGE(0, 0);
    __syncthreads();
    int buf = 0;
    for (int t = 0; t < NT; ++t) {
        if (t + 1 < NT) STAGE(buf ^ 32768, t + 1);
        COMPUTE(buf);
        __syncthreads();
        buf ^= 32768;
    }

    // ---- epilogue: D frag mapping col=lane&15, row=(lane>>4)*4+r
    const int erow0 = m0 + wr * 64 + ((lane >> 4) << 2);
    if (of32) {
        const int col0 = n0 + wc * 64 + rl;
        #pragma unroll
        for (int mf = 0; mf < 4; ++mf)
            #pragma unroll
            for (int nf = 0; nf < 4; ++nf)
                #pragma unroll
                for (int r = 0; r < 4; ++r)
                    of32[(size_t)(erow0 + mf * 16 + r) * CDIM + (col0 + nf * 16)] =
                        acc[mf][nf][r];
    } else {
        const int mat  = nt / 6;
        const int col0 = (nt - mat * 6) * 128 + wc * 64 + rl;
        _Float16* o = (mat == 0) ? o0 : ((mat == 1) ? o1 : o2);
        if (mat == 2) {
            #pragma unroll
            for (int mf = 0; mf < 4; ++mf)
                #pragma unroll
                for (int nf = 0; nf < 4; ++nf)
                    #pragma unroll
                    for (int r = 0; r < 4; ++r)
                        o[(size_t)(erow0 + mf * 16 + r) * CDIM + (col0 + nf * 16)] =
                            (_Float16)(1.0f / (1.0f + __expf(-acc[mf][nf][r])));
        } else {
            #pragma unroll
            for (int mf = 0; mf < 4; ++mf)
                #pragma unroll
                for (int nf = 0; nf < 4; ++nf)
                    #pragma unroll
                    for (int r = 0; r < 4; ++r)
                        o[(size_t)(erow0 + mf * 16 + r) * CDIM + (col0 + nf * 16)] =
                            (_Float16)acc[mf][nf][r];
        }
    }
}

// ---------------------------------------------------------------------------
// WKV (math verified rounds 2-15)
// ---------------------------------------------------------------------------
#define WKV_STEP(a, bb, p, kt, vt, w)                \
    {                                                \
        const float pn = fmaxf((p) - (w), (kt));     \
        const float e1 = __expf((p) - (w) - pn);     \
        const float e2 = __expf((kt) - pn);          \
        (a)  = e1 * (a)  + e2 * (vt);                \
        (bb) = e1 * (bb) + e2;                       \
        (p)  = pn;                                   \
    }

// phase1: 2 ch/thread. 384 threads = 768 channels; grid (NCH, curb).
__global__ __launch_bounds__(384) void wkv_phase1(
    const _Float16* __restrict__ k, const _Float16* __restrict__ v,
    const float* __restrict__ decay,
    float* __restrict__ Sfa, float* __restrict__ Sfb, float* __restrict__ Sfp,
    float* __restrict__ Sba, float* __restrict__ Sbb, float* __restrict__ Sbp) {
    const int c0 = threadIdx.x * 2;
    const int j = blockIdx.x;
    const int b = blockIdx.y;
    const float2v d2 = *(const float2v*)(decay + c0);
    const float w0 = d2.x * (1.0f / (float)TLEN);
    const float w1 = d2.y * (1.0f / (float)TLEN);

    const size_t base = ((size_t)b * TLEN + (size_t)j * LCH) * CDIM + c0;
    unsigned kt2[LCH], vt2[LCH];
    #pragma unroll
    for (int i = 0; i < LCH; ++i) {
        kt2[i] = *(const unsigned*)(k + base + (size_t)i * CDIM);
        vt2[i] = *(const unsigned*)(v + base + (size_t)i * CDIM);
    }

    const size_t idx = ((size_t)b * NCH + j) * CDIM + c0;

    {
        float a0 = 0.f, b0 = 0.f, p0 = -1e38f, a1 = 0.f, b1 = 0.f, p1 = -1e38f;
        #pragma unroll
        for (int i = 0; i < LCH; ++i) {
            WKV_STEP(a0, b0, p0, lo16(kt2[i]), lo16(vt2[i]), w0);
            WKV_STEP(a1, b1, p1, hi16(kt2[i]), hi16(vt2[i]), w1);
        }
        *(float2v*)(Sfa + idx) = (float2v){a0, a1};
        *(float2v*)(Sfb + idx) = (float2v){b0, b1};
        *(float2v*)(Sfp + idx) = (float2v){p0, p1};
    }
    {
        float a0 = 0.f, b0 = 0.f, p0 = -1e38f, a1 = 0.f, b1 = 0.f, p1 = -1e38f;
        #pragma unroll
        for (int i = LCH - 1; i >= 0; --i) {
            WKV_STEP(a0, b0, p0, lo16(kt2[i]), lo16(vt2[i]), w0);
            WKV_STEP(a1, b1, p1, hi16(kt2[i]), hi16(vt2[i]), w1);
        }
        *(float2v*)(Sba + idx) = (float2v){a0, a1};
        *(float2v*)(Sbb + idx) = (float2v){b0, b1};
        *(float2v*)(Sbp + idx) = (float2v){p0, p1};
    }
}

#define WKV_COMBINE(a, bb, p, as, bs, ps, wL)        \
    {                                                \
        const float pn = fmaxf((p) - (wL), (ps));    \
        const float e1 = __expf((p) - (wL) - pn);    \
        const float e2 = __expf((ps) - pn);          \
        (a)  = e1 * (a)  + e2 * (as);                \
        (bb) = e1 * (bb) + e2 * (bs);                \
        (p)  = pn;                                   \
    }

// phase2: 1 ch/thread (latency-bound). grid (CDIM/64, curb, 2).
__global__ __launch_bounds__(64) void wkv_phase2(
    const float* __restrict__ Sfa, const float* __restrict__ Sfb, const float* __restrict__ Sfp,
    const float* __restrict__ Sba, const float* __restrict__ Sbb, const float* __restrict__ Sbp,
    const float* __restrict__ decay,
    float* __restrict__ Lina, float* __restrict__ Linb, float* __restrict__ Linp,
    float* __restrict__ Rina, float* __restrict__ Rinb, float* __restrict__ Rinp) {
    const int c = blockIdx.x * 64 + threadIdx.x;
    const int b = blockIdx.y;
    const int dir = blockIdx.z;
    const float wL = decay[c] * ((float)LCH / (float)TLEN);

    const float* Sa = dir ? Sba : Sfa;
    const float* Sb = dir ? Sbb : Sfb;
    const float* Sp = dir ? Sbp : Sfp;
    float* Oa = dir ? Rina : Lina;
    float* Ob = dir ? Rinb : Linb;
    float* Op = dir ? Rinp : Linp;

    const size_t base = (size_t)b * NCH * CDIM + c;
    auto IDX = [&](int j) {
        return base + (size_t)(dir ? (NCH - 1 - j) : j) * CDIM;
    };

    float gaA[4], gbA[4], gpA[4], gaB[4], gbB[4], gpB[4];
    #pragma unroll
    for (int u = 0; u < 4; ++u) {
        const size_t id = IDX(u);
        gaA[u] = Sa[id]; gbA[u] = Sb[id]; gpA[u] = Sp[id];
    }
    float a = 0.0f, bb = 0.0f, p = -1e38f;

    for (int jg = 0; jg < NCH; jg += 8) {
        #pragma unroll
        for (int u = 0; u < 4; ++u) {
            const size_t id = IDX(jg + 4 + u);
            gaB[u] = Sa[id]; gbB[u] = Sb[id]; gpB[u] = Sp[id];
        }
        #pragma unroll
        for (int u = 0; u < 4; ++u) {
            const size_t id = IDX(jg + u);
            Oa[id] = a; Ob[id] = bb; Op[id] = p;
            WKV_COMBINE(a, bb, p, gaA[u], gbA[u], gpA[u], wL);
        }
        if (jg + 8 < NCH) {
            #pragma unroll
            for (int u = 0; u < 4; ++u) {
                const size_t id = IDX(jg + 8 + u);
                gaA[u] = Sa[id]; gbA[u] = Sb[id]; gpA[u] = Sp[id];
            }
        }
        #pragma unroll
        for (int u = 0; u < 4; ++u) {
            const size_t id = IDX(jg + 4 + u);
            Oa[id] = a; Ob[id] = bb; Op[id] = p;
            WKV_COMBINE(a, bb, p, gaB[u], gbB[u], gpB[u], wL);
        }
    }
}

// phase3: 1 ch/thread; k/v/sr reloaded inline per pass (they're L2/L3-hot) —
// drops the kt/vt register caches (-64 VGPR) for higher occupancy.
// grid (CDIM/256, NCH, curb), 256 thr.
__global__ __launch_bounds__(256) void wkv_phase3(
    const _Float16* __restrict__ k, const _Float16* __restrict__ v,
    const _Float16* __restrict__ sr,
    const float* __restrict__ Lina, const float* __restrict__ Linb, const float* __restrict__ Linp,
    const float* __restrict__ Rina, const float* __restrict__ Rinb, const float* __restrict__ Rinp,
    const float* __restrict__ decay, const float* __restrict__ first,
    _Float16* __restrict__ zh) {
    const int c = blockIdx.x * 256 + threadIdx.x;
    const int j = blockIdx.y;
    const int b = blockIdx.z;
    const float w = decay[c] * (1.0f / (float)TLEN);
    const float u = first[c] * (1.0f / (float)TLEN);

    const size_t base = ((size_t)b * TLEN + (size_t)j * LCH) * CDIM + c;
    const size_t idx = ((size_t)b * NCH + j) * CDIM + c;

    float ar[LCH], br[LCH], pr[LCH];
    {
        float a = Rina[idx], bb = Rinb[idx], p = Rinp[idx];
        #pragma unroll
        for (int i = LCH - 1; i >= 0; --i) {
            ar[i] = a; br[i] = bb; pr[i] = p;
            const size_t off = base + (size_t)i * CDIM;
            const float kt = (float)k[off];
            const float vt = (float)v[off];
            WKV_STEP(a, bb, p, kt, vt, w);
        }
    }
    {
        float a = Lina[idx], bb = Linb[idx], p = Linp[idx];
        #pragma unroll
        for (int i = 0; i < LCH; ++i) {
            const size_t off = base + (size_t)i * CDIM;
            const float kt  = (float)k[off];
            const float vt  = (float)v[off];
            const float srt = (float)sr[off];
            const float ps = u + kt;
            const float q  = fmaxf(fmaxf(p, pr[i]), ps);
            const float eL = __expf(p - q);
            const float eR = __expf(pr[i] - q);
            const float eS = __expf(ps - q);
            const float num = eL * a  + eR * ar[i] + eS * vt;
            const float den = eL * bb + eR * br[i] + eS;
            zh[off] = (_Float16)(srt * (num / den));
            WKV_STEP(a, bb, p, kt, vt, w);
        }
    }
}

// ---------------------------------------------------------------------------
// Driver. ws: [Wcat 3*WN f16 | Woh WN f16 | 12 state f32 planes | kh vh srh
// xh f16 planes (zh aliases xh)]. Batch-chunked to fit ws_size.
// ---------------------------------------------------------------------------
extern "C" void kernel_launch(void* const* d_in, const int* in_sizes, int n_in,
                              void* d_out, int out_size, void* d_ws, size_t ws_size,
                              hipStream_t stream) {
    const float* x     = (const float*)d_in[0];
    const float* Wk    = (const float*)d_in[1];
    const float* Wv    = (const float*)d_in[2];
    const float* Wr    = (const float*)d_in[3];
    const float* Wo    = (const float*)d_in[4];
    const float* decay = (const float*)d_in[5];
    const float* first = (const float*)d_in[6];
    float* out = (float*)d_out;

    const size_t WN = (size_t)CDIM * CDIM;
    const size_t wbytes = 4 * WN * sizeof(_Float16);
    const size_t per_b  = (size_t)TLEN * CDIM * 8 + 12ull * NCH * CDIM * 4; // 17.3 MB
    if (ws_size < wbytes + per_b) return;
    int nb = (int)((ws_size - wbytes) / per_b);
    if (nb > BSZ) nb = BSZ;

    _Float16* wsp  = (_Float16*)d_ws;
    _Float16* Wcat = wsp;                 // rows 0-767 Wk, 768-1535 Wv, 1536-2303 Wr
    _Float16* Woh  = wsp + 3 * WN;

    const size_t NE = (size_t)nb * TLEN * CDIM;
    const size_t NP = (size_t)nb * NCH * CDIM;
    float* Sfa = (float*)(wsp + 4 * WN);
    float* Sfb = Sfa + NP;  float* Sfp = Sfb + NP;
    float* Sba = Sfp + NP;  float* Sbb = Sba + NP;  float* Sbp = Sbb + NP;
    float* Lina = Sbp + NP; float* Linb = Lina + NP; float* Linp = Linb + NP;
    float* Rina = Linp + NP; float* Rinb = Rina + NP; float* Rinp = Rinb + NP;
    _Float16* kh  = (_Float16*)(Rinp + NP);
    _Float16* vh  = kh + NE;
    _Float16* srh = vh + NE;
    _Float16* xh  = srh + NE;
    _Float16* zh  = xh;   // alias: phase3 runs after the merged input GEMM

    split_w4<<<dim3((int)(WN / 1024), 4), dim3(256), 0, stream>>>(
        Wk, Wv, Wr, Wo, Wcat, Woh, (int)(WN / 4));

    for (int b0 = 0; b0 < BSZ; b0 += nb) {
        const int curb = (BSZ - b0 < nb) ? (BSZ - b0) : nb;
        const int rows = curb * TLEN;
        const float* xc = x   + (size_t)b0 * TLEN * CDIM;
        float*       oc = out + (size_t)b0 * TLEN * CDIM;

        const int n4 = rows * CDIM / 4;
        split_f16<<<dim3(n4 / 256), dim3(256), 0, stream>>>(xc, xh, n4);

        const int mtiles = rows / 128;     // divisible by 8
        const int mpx    = mtiles / 8;

        // merged k|v|sr GEMM: Wcat 2304 rows -> 18 ntiles of 128
        gemm_128<<<dim3(mtiles * 18), dim3(256), 0, stream>>>(
            xh, Wcat, kh, vh, srh, nullptr, mpx, 18);

        wkv_phase1<<<dim3(NCH, curb), dim3(384), 0, stream>>>(
            kh, vh, decay, Sfa, Sfb, Sfp, Sba, Sbb, Sbp);
        wkv_phase2<<<dim3(CDIM / 64, curb, 2), dim3(64), 0, stream>>>(
            Sfa, Sfb, Sfp, Sba, Sbb, Sbp, decay,
            Lina, Linb, Linp, Rina, Rinb, Rinp);
        wkv_phase3<<<dim3(CDIM / 256, NCH, curb), dim3(256), 0, stream>>>(
            kh, vh, srh, Lina, Linb, Linp, Rina, Rinb, Rinp, decay, first, zh);

        // Wo GEMM: 6 ntiles of 128, f32 output
        gemm_128<<<dim3(mtiles * 6), dim3(256), 0, stream>>>(
            zh, Woh, nullptr, nullptr, nullptr, oc, mpx, 6);
    }
}